// Round 5
// baseline (114.024 us; speedup 1.0000x reference)
//
#include <hip/hip_runtime.h>

#define HW   16384            // 128*128
#define NPIX 65536            // 4*HW

typedef _Float16 f16x2 __attribute__((ext_vector_type(2)));

#if __has_builtin(__builtin_amdgcn_fdot2)
#define DOT2(a, b, c) __builtin_amdgcn_fdot2((a), (b), (c), false)
#else
__device__ __forceinline__ float dot2_fb(f16x2 a, f16x2 b, float c) {
    return fmaf((float)a.x, (float)b.x, fmaf((float)a.y, (float)b.y, c));
}
#define DOT2(a, b, c) dot2_fb((a), (b), (c))
#endif

#if __has_builtin(__builtin_amdgcn_exp2f)
#define EXP2F(x) __builtin_amdgcn_exp2f(x)
#else
#define EXP2F(x) exp2f(x)
#endif

__device__ __forceinline__ unsigned packh2(float a, float b) {
    f16x2 h; h.x = (_Float16)a; h.y = (_Float16)b;
    return __builtin_bit_cast(unsigned, h);
}
__device__ __forceinline__ f16x2 bch(unsigned u) {
    return __builtin_bit_cast(f16x2, u);
}

// ---------------------------------------------------------------------------
// Pass 1: 1x1 conv. blockIdx.y = matrix (0: f1, 1: f2 + rec/bilinear).
// 512 blocks x 256 thr = 2 waves/SIMD. delta (64 f32) prefetched to VGPRs;
// weight rows are consecutive uniform f32 -> s_load from K$.
// ---------------------------------------------------------------------------
__global__ __launch_bounds__(256) void pass1_kernel(
    const float* __restrict__ delta, const float* __restrict__ outlo,
    const float* __restrict__ w1, const float* __restrict__ b1,
    const float* __restrict__ w2, const float* __restrict__ b2,
    uint4* __restrict__ f1p4, uint4* __restrict__ f2p4, float2* __restrict__ recp)
{
    const int m = blockIdx.y;
    const int g = blockIdx.x * 256 + threadIdx.x;   // 0..65535
    const int n = g >> 14;
    const int p = g & (HW - 1);

    const float* __restrict__ wm = m ? w2 : w1;
    const float* __restrict__ bm = m ? b2 : b1;

    float d[64];
    const float* db = delta + (size_t)n * 64 * HW + p;
#pragma unroll
    for (int c = 0; c < 64; ++c) d[c] = db[(size_t)c * HW];

    float acc[16];
#pragma unroll
    for (int o = 0; o < 16; ++o) {
        float a = bm[o];
        const float* wr = wm + o * 64;    // uniform, 64 consecutive f32
#pragma unroll
        for (int c = 0; c < 64; ++c) a = fmaf(wr[c], d[c], a);
        acc[o] = a;
    }

    uint4* dst = m ? f2p4 : f1p4;
    uint4 q;
    q.x = packh2(acc[0], acc[1]);   q.y = packh2(acc[2], acc[3]);
    q.z = packh2(acc[4], acc[5]);   q.w = packh2(acc[6], acc[7]);
    dst[g] = q;
    q.x = packh2(acc[8], acc[9]);   q.y = packh2(acc[10], acc[11]);
    q.z = packh2(acc[12], acc[13]); q.w = packh2(acc[14], acc[15]);
    dst[NPIX + g] = q;

    if (m) {
        float f2sq = 0.f;
#pragma unroll
        for (int o = 0; o < 16; ++o) f2sq = fmaf(acc[o], acc[o], f2sq);

        // bilinear align_corners upsample of out [N,2,64,64] at (y,x)
        const int y = p >> 7, x = p & 127;
        const float ys = (float)(y * 63) / 127.0f;
        const float xs = (float)(x * 63) / 127.0f;
        const int iy0 = (int)ys, ix0 = (int)xs;
        const float fy = ys - (float)iy0, fx = xs - (float)ix0;
        const int iy1 = min(iy0 + 1, 63), ix1 = min(ix0 + 1, 63);
        const float* ob = outlo + n * 2 * 4096;
        float o01[2];
#pragma unroll
        for (int cc = 0; cc < 2; ++cc) {
            const float* oc = ob + cc * 4096;
            const float v00 = oc[iy0*64+ix0], v01 = oc[iy0*64+ix1];
            const float v10 = oc[iy1*64+ix0], v11 = oc[iy1*64+ix1];
            const float top = v00 + fx * (v01 - v00);
            const float bot = v10 + fx * (v11 - v10);
            o01[cc] = top + fy * (bot - top);
        }
        float2 rc;
        rc.x = __builtin_bit_cast(float, packh2(o01[0], o01[1]));
        rc.y = f2sq;
        recp[g] = rc;
    }
}

// ---------------------------------------------------------------------------
// Pass 2: tile 64x4 px, vertical pairs (y,y+1): 128 pairs; 8 waves/block
// (wave = 64 consecutive x at one (pyr, h)) -> 256 blocks x 512 thr =
// 2 waves/SIMD, 1 block/CU. All ab taps for the thread prefetched to regs
// BEFORE the halo fill + barrier (latency hidden). Halo 12x72 records staged
// plane-major; within a wave all lanes read the same LDS row at consecutive
// 16B -> uniform bank sweep. 4 h-waves split the 10 tap rows (dyc=h,h+4,h+8);
// partials reduced via LDS.
// ---------------------------------------------------------------------------
__global__ __launch_bounds__(512) void pass2_kernel(
    const uint4* __restrict__ f1p4, const uint4* __restrict__ f2p4,
    const float2* __restrict__ recp, const float* __restrict__ ab,
    const float* __restrict__ gdp, const float* __restrict__ gsp,
    float* __restrict__ outp)
{
    __shared__ uint4  shA[12 * 72];     // f2 ch0-7
    __shared__ uint4  shB[12 * 72];     // f2 ch8-15
    __shared__ float2 shC[12 * 72];     // {half2{o0,o1}, f2sq}
    __shared__ float  shP[6 * 4 * 128]; // [val][h][pair]

    const int t = threadIdx.x;
    const int n = blockIdx.z;
    const int bx = blockIdx.x * 64, by = blockIdx.y * 4;

    const int w   = t >> 6;         // wave 0..7
    const int wh  = w & 3;          // h-split
    const int pyr = w >> 2;         // pair-row 0..1
    const int px  = t & 63;         // lane = x within tile
    const int pairid = pyr * 64 + px;
    const int p0 = (by + pyr * 2) * 128 + bx + px;   // upper pixel of pair
    const int g0 = n * HW + p0;

    // ---- prefetch ALL ab taps for this thread (hidden behind fill+barrier) ----
    const float* abn = ab + (size_t)n * 81 * HW;
    const int nrows = (wh < 2) ? 3 : 2;   // dyc = wh + 4r <= 9
    float a0v[3][9], a1v[3][9];
#pragma unroll
    for (int r = 0; r < 3; ++r) {
        if (r < nrows) {
            const int dyc = wh + r * 4;
            if (dyc <= 8) {
                const float* pp = abn + (size_t)(dyc * 9) * HW + p0;
#pragma unroll
                for (int j = 0; j < 9; ++j) a0v[r][j] = pp[(size_t)j * HW];
            }
            if (dyc >= 1) {
                const float* pp = abn + (size_t)((dyc - 1) * 9) * HW + p0 + 128;
#pragma unroll
                for (int j = 0; j < 9; ++j) a1v[r][j] = pp[(size_t)j * HW];
            }
        }
    }

    // ---- f1 fragments (issued before barrier) ----
    const uint4 A0 = f1p4[g0],       A1 = f1p4[NPIX + g0];
    const uint4 B0 = f1p4[g0 + 128], B1 = f1p4[NPIX + g0 + 128];

    // ---- fill 12x72 halo ----
#pragma unroll
    for (int s = 0; s < 2; ++s) {
        const int idx = t + s * 512;
        if (idx < 864) {
            const int hy = idx / 72, hx = idx - hy * 72;
            int gy = by - 4 + hy; gy = gy < 0 ? -gy : (gy > 127 ? 254 - gy : gy);
            int gx = bx - 4 + hx; gx = gx < 0 ? -gx : (gx > 127 ? 254 - gx : gx);
            const int gg = n * HW + gy * 128 + gx;
            shA[idx] = f2p4[gg];
            shB[idx] = f2p4[NPIX + gg];
            shC[idx] = recp[gg];
        }
    }
    __syncthreads();

    const float gd = gdp[0], gs = gsp[0];
    const float L2E = 1.44269504088896f;
    const float g2 = 2.0f * gd * L2E, mg = -gd * L2E, gsl = gs * L2E;

    f16x2 f1a[8], f1b[8];
    f1a[0]=bch(A0.x); f1a[1]=bch(A0.y); f1a[2]=bch(A0.z); f1a[3]=bch(A0.w);
    f1a[4]=bch(A1.x); f1a[5]=bch(A1.y); f1a[6]=bch(A1.z); f1a[7]=bch(A1.w);
    f1b[0]=bch(B0.x); f1b[1]=bch(B0.y); f1b[2]=bch(B0.z); f1b[3]=bch(B0.w);
    f1b[4]=bch(B1.x); f1b[5]=bch(B1.y); f1b[6]=bch(B1.z); f1b[7]=bch(B1.w);
    float f1sqa = 0.f, f1sqb = 0.f;
#pragma unroll
    for (int k = 0; k < 8; ++k) {
        f1sqa = DOT2(f1a[k], f1a[k], f1sqa);
        f1sqb = DOT2(f1b[k], f1b[k], f1sqb);
    }
    const float c0a = mg * f1sqa;
    const float c0b = mg * f1sqb;

    float s0 = 0.f, x00 = 0.f, x01 = 0.f;
    float s1 = 0.f, x10 = 0.f, x11 = 0.f;

#pragma unroll
    for (int r = 0; r < 3; ++r) {
        if (r < nrows) {
            const int dyc = wh + r * 4;            // wave-uniform
            const bool has0 = (dyc <= 8);
            const bool has1 = (dyc >= 1);
            const int rib = (pyr * 2 + dyc) * 72 + px;
#pragma unroll
            for (int j = 0; j < 9; ++j) {
                const uint4  q0 = shA[rib + j];
                const uint4  q1 = shB[rib + j];
                const float2 rc = shC[rib + j];
                const f16x2 v0 = bch(q0.x), v1 = bch(q0.y), v2 = bch(q0.z), v3 = bch(q0.w);
                const f16x2 v4 = bch(q1.x), v5 = bch(q1.y), v6 = bch(q1.z), v7 = bch(q1.w);
                const f16x2 oh = bch(__builtin_bit_cast(unsigned, rc.x));
                const float o0f = (float)oh.x, o1f = (float)oh.y;
                const float f2s = rc.y;
                if (has0) {
                    float dt = DOT2(f1a[0], v0, 0.f);
                    dt = DOT2(f1a[1], v1, dt); dt = DOT2(f1a[2], v2, dt);
                    dt = DOT2(f1a[3], v3, dt); dt = DOT2(f1a[4], v4, dt);
                    dt = DOT2(f1a[5], v5, dt); dt = DOT2(f1a[6], v6, dt);
                    dt = DOT2(f1a[7], v7, dt);
                    float e = fmaf(g2, dt, c0a);
                    e = fmaf(mg, f2s, e);
                    e = fmaf(gsl, a0v[r][j], e);
                    const float wgt = EXP2F(e);
                    s0 += wgt; x00 = fmaf(wgt, o0f, x00); x01 = fmaf(wgt, o1f, x01);
                }
                if (has1) {
                    float dt = DOT2(f1b[0], v0, 0.f);
                    dt = DOT2(f1b[1], v1, dt); dt = DOT2(f1b[2], v2, dt);
                    dt = DOT2(f1b[3], v3, dt); dt = DOT2(f1b[4], v4, dt);
                    dt = DOT2(f1b[5], v5, dt); dt = DOT2(f1b[6], v6, dt);
                    dt = DOT2(f1b[7], v7, dt);
                    float e = fmaf(g2, dt, c0b);
                    e = fmaf(mg, f2s, e);
                    e = fmaf(gsl, a1v[r][j], e);
                    const float wgt = EXP2F(e);
                    s1 += wgt; x10 = fmaf(wgt, o0f, x10); x11 = fmaf(wgt, o1f, x11);
                }
            }
        }
    }

    shP[(0 * 4 + wh) * 128 + pairid] = s0;
    shP[(1 * 4 + wh) * 128 + pairid] = x00;
    shP[(2 * 4 + wh) * 128 + pairid] = x01;
    shP[(3 * 4 + wh) * 128 + pairid] = s1;
    shP[(4 * 4 + wh) * 128 + pairid] = x10;
    shP[(5 * 4 + wh) * 128 + pairid] = x11;
    __syncthreads();

    if (t < 128) {
        float v[6];
#pragma unroll
        for (int k = 0; k < 6; ++k) {
            const float* pp = &shP[k * 512 + t];
            v[k] = (pp[0] + pp[128]) + (pp[256] + pp[384]);
        }
        const int qx = t & 63, qyr = t >> 6;
        const int pp0 = (by + qyr * 2) * 128 + bx + qx;
        const float i0 = 1.0f / v[0], i1 = 1.0f / v[3];
        float* o0 = outp + (size_t)(n * 2 + 0) * HW;
        float* o1 = outp + (size_t)(n * 2 + 1) * HW;
        o0[pp0]       = v[1] * i0;
        o1[pp0]       = v[2] * i0;
        o0[pp0 + 128] = v[4] * i1;
        o1[pp0 + 128] = v[5] * i1;
    }
}

extern "C" void kernel_launch(void* const* d_in, const int* in_sizes, int n_in,
                              void* d_out, int out_size, void* d_ws, size_t ws_size,
                              hipStream_t stream) {
    const float* delta = (const float*)d_in[0];   // [4,64,128,128]
    const float* outlo = (const float*)d_in[1];   // [4,2,64,64]
    const float* ab    = (const float*)d_in[2];   // [4,81,16384]
    const float* w1    = (const float*)d_in[3];   // [16,64]
    const float* b1    = (const float*)d_in[4];   // [16]
    const float* w2    = (const float*)d_in[5];   // [16,64]
    const float* b2    = (const float*)d_in[6];   // [16]
    const float* gd    = (const float*)d_in[7];   // scalar
    const float* gs    = (const float*)d_in[8];   // scalar
    float* outp = (float*)d_out;                  // [4,2,128,128]

    uint4*  f1p4 = (uint4*)d_ws;                  // 2 MiB
    uint4*  f2p4 = f1p4 + (size_t)2 * NPIX;       // 2 MiB
    float2* recp = (float2*)(f2p4 + (size_t)2 * NPIX); // 512 KiB

    pass1_kernel<<<dim3(256, 2), dim3(256), 0, stream>>>(delta, outlo, w1, b1, w2, b2,
                                                         f1p4, f2p4, recp);
    pass2_kernel<<<dim3(2, 32, 4), dim3(512), 0, stream>>>(f1p4, f2p4, recp, ab,
                                                           gd, gs, outp);
}

// Round 6
// 112.735 us; speedup vs baseline: 1.0114x; 1.0114x over previous
//
#include <hip/hip_runtime.h>

#define HW   16384            // 128*128
#define NPIX 65536            // 4*HW

typedef _Float16 f16x2 __attribute__((ext_vector_type(2)));

#if __has_builtin(__builtin_amdgcn_fdot2)
#define DOT2(a, b, c) __builtin_amdgcn_fdot2((a), (b), (c), false)
#else
__device__ __forceinline__ float dot2_fb(f16x2 a, f16x2 b, float c) {
    return fmaf((float)a.x, (float)b.x, fmaf((float)a.y, (float)b.y, c));
}
#define DOT2(a, b, c) dot2_fb((a), (b), (c))
#endif

#if __has_builtin(__builtin_amdgcn_exp2f)
#define EXP2F(x) __builtin_amdgcn_exp2f(x)
#else
#define EXP2F(x) exp2f(x)
#endif

__device__ __forceinline__ unsigned packh2(float a, float b) {
    f16x2 h; h.x = (_Float16)a; h.y = (_Float16)b;
    return __builtin_bit_cast(unsigned, h);
}
__device__ __forceinline__ f16x2 bch(unsigned u) {
    return __builtin_bit_cast(f16x2, u);
}

// ---------------------------------------------------------------------------
// Pass 1: 1x1 convs, channel-split for occupancy. Block = 256 thr = 64 px x
// 4 chunks (16 ch each); both matrices per block (delta read once). Partials
// via 32 KB LDS; waves 0-1 finalize (m=0: f1, m=1: f2 + f2sq + bilinear rec).
// 1024 blocks, 4 blocks/CU -> 4 waves/SIMD.
// ---------------------------------------------------------------------------
__global__ __launch_bounds__(256) void pass1_kernel(
    const float* __restrict__ delta, const float* __restrict__ outlo,
    const float* __restrict__ w1, const float* __restrict__ b1,
    const float* __restrict__ w2, const float* __restrict__ b2,
    uint4* __restrict__ f1p4, uint4* __restrict__ f2p4, float2* __restrict__ recp)
{
    __shared__ float4 shW[32][64];   // [(m*4+cc)*4+o4][px]

    const int t  = threadIdx.x;
    const int px = t & 63, cc = t >> 6;     // wave-uniform chunk
    const int g0 = blockIdx.x * 64;
    const int n  = g0 >> 14;
    const int p  = (g0 & (HW - 1)) + px;

    float d[16];
    const float* db = delta + (size_t)n * 64 * HW + p;
#pragma unroll
    for (int j = 0; j < 16; ++j) d[j] = db[(size_t)(cc * 16 + j) * HW];

    float a1[16], a2[16];
    const float* wr1 = w1 + cc * 16;        // wave-uniform -> s_load
    const float* wr2 = w2 + cc * 16;
#pragma unroll
    for (int o = 0; o < 16; ++o) {
        float s1 = 0.f, s2 = 0.f;
        const float* q1 = wr1 + o * 64;
        const float* q2 = wr2 + o * 64;
#pragma unroll
        for (int j = 0; j < 16; ++j) {
            s1 = fmaf(q1[j], d[j], s1);
            s2 = fmaf(q2[j], d[j], s2);
        }
        a1[o] = s1; a2[o] = s2;
    }

#pragma unroll
    for (int o4 = 0; o4 < 4; ++o4) {
        shW[cc * 4 + o4][px]       = make_float4(a1[o4*4], a1[o4*4+1], a1[o4*4+2], a1[o4*4+3]);
        shW[16 + cc * 4 + o4][px]  = make_float4(a2[o4*4], a2[o4*4+1], a2[o4*4+2], a2[o4*4+3]);
    }
    __syncthreads();

    if (t < 128) {
        const int m = t >> 6, qx = t & 63;  // wave-uniform m
        const float* bm = m ? b2 : b1;
        float acc[16];
#pragma unroll
        for (int o4 = 0; o4 < 4; ++o4) {
            float4 s = shW[m * 16 + o4][qx];
#pragma unroll
            for (int c = 1; c < 4; ++c) {
                const float4 v = shW[m * 16 + c * 4 + o4][qx];
                s.x += v.x; s.y += v.y; s.z += v.z; s.w += v.w;
            }
            acc[o4*4]   = s.x + bm[o4*4];
            acc[o4*4+1] = s.y + bm[o4*4+1];
            acc[o4*4+2] = s.z + bm[o4*4+2];
            acc[o4*4+3] = s.w + bm[o4*4+3];
        }

        const int g = g0 + qx;
        uint4* dst = m ? f2p4 : f1p4;
        uint4 q;
        q.x = packh2(acc[0], acc[1]);   q.y = packh2(acc[2], acc[3]);
        q.z = packh2(acc[4], acc[5]);   q.w = packh2(acc[6], acc[7]);
        dst[g] = q;
        q.x = packh2(acc[8], acc[9]);   q.y = packh2(acc[10], acc[11]);
        q.z = packh2(acc[12], acc[13]); q.w = packh2(acc[14], acc[15]);
        dst[NPIX + g] = q;

        if (m) {
            float f2sq = 0.f;
#pragma unroll
            for (int o = 0; o < 16; ++o) f2sq = fmaf(acc[o], acc[o], f2sq);

            const int pq = g & (HW - 1);
            const int y = pq >> 7, x = pq & 127;
            const float ys = (float)(y * 63) / 127.0f;
            const float xs = (float)(x * 63) / 127.0f;
            const int iy0 = (int)ys, ix0 = (int)xs;
            const float fy = ys - (float)iy0, fx = xs - (float)ix0;
            const int iy1 = min(iy0 + 1, 63), ix1 = min(ix0 + 1, 63);
            const float* ob = outlo + n * 2 * 4096;
            float o01[2];
#pragma unroll
            for (int ch = 0; ch < 2; ++ch) {
                const float* oc = ob + ch * 4096;
                const float v00 = oc[iy0*64+ix0], v01 = oc[iy0*64+ix1];
                const float v10 = oc[iy1*64+ix0], v11 = oc[iy1*64+ix1];
                const float top = v00 + fx * (v01 - v00);
                const float bot = v10 + fx * (v11 - v10);
                o01[ch] = top + fy * (bot - top);
            }
            float2 rc;
            rc.x = __builtin_bit_cast(float, packh2(o01[0], o01[1]));
            rc.y = f2sq;
            recp[g] = rc;
        }
    }
}

// ---------------------------------------------------------------------------
// Pass 2: tile 64x2 (vertical pairs y0,y0+1 per lane x), 8 waves = 8 tap-row
// groups (dyc = wh, wh+8). 512 blocks x 512 thr, ~41 KB LDS -> 3 blocks/CU =
// 6 waves/SIMD. ab (<=36 regs) prefetched before the halo-fill barrier.
// Halo 10x72 records plane-major; lanes read consecutive 16B -> no conflicts.
// ---------------------------------------------------------------------------
__global__ __launch_bounds__(512) void pass2_kernel(
    const uint4* __restrict__ f1p4, const uint4* __restrict__ f2p4,
    const float2* __restrict__ recp, const float* __restrict__ ab,
    const float* __restrict__ gdp, const float* __restrict__ gsp,
    float* __restrict__ outp)
{
    __shared__ uint4  shA[10 * 72];
    __shared__ uint4  shB[10 * 72];
    __shared__ float2 shC[10 * 72];
    __shared__ float  shP[6 * 8 * 64];

    const int t = threadIdx.x;
    const int n = blockIdx.z;
    const int bx = blockIdx.x * 64, y0 = blockIdx.y * 2;

    const int wh = t >> 6;          // 0..7: tap-row group
    const int px = t & 63;
    const int p0 = y0 * 128 + bx + px;     // upper pixel
    const int g0 = n * HW + p0;

    // ---- prefetch ab taps (2 rows max) before the barrier ----
    const float* abn = ab + (size_t)n * 81 * HW;
    const int nr = (wh < 2) ? 2 : 1;       // dyc = wh, wh+8
    float a0v[2][9], a1v[2][9];
#pragma unroll
    for (int r = 0; r < 2; ++r) {
        if (r < nr) {
            const int dyc = wh + r * 8;
            if (dyc <= 8) {
                const float* pp = abn + (size_t)(dyc * 9) * HW + p0;
#pragma unroll
                for (int j = 0; j < 9; ++j) a0v[r][j] = pp[(size_t)j * HW];
            }
            if (dyc >= 1) {
                const float* pp = abn + (size_t)((dyc - 1) * 9) * HW + p0 + 128;
#pragma unroll
                for (int j = 0; j < 9; ++j) a1v[r][j] = pp[(size_t)j * HW];
            }
        }
    }

    const uint4 A0 = f1p4[g0],       A1 = f1p4[NPIX + g0];
    const uint4 B0 = f1p4[g0 + 128], B1 = f1p4[NPIX + g0 + 128];

    // ---- fill 10x72 halo ----
#pragma unroll
    for (int s = 0; s < 2; ++s) {
        const int idx = t + s * 512;
        if (idx < 720) {
            const int hy = idx / 72, hx = idx - hy * 72;
            int gy = y0 - 4 + hy; gy = gy < 0 ? -gy : (gy > 127 ? 254 - gy : gy);
            int gx = bx - 4 + hx; gx = gx < 0 ? -gx : (gx > 127 ? 254 - gx : gx);
            const int gg = n * HW + gy * 128 + gx;
            shA[idx] = f2p4[gg];
            shB[idx] = f2p4[NPIX + gg];
            shC[idx] = recp[gg];
        }
    }
    __syncthreads();

    const float gd = gdp[0], gs = gsp[0];
    const float L2E = 1.44269504088896f;
    const float g2 = 2.0f * gd * L2E, mg = -gd * L2E, gsl = gs * L2E;

    f16x2 f1a[8], f1b[8];
    f1a[0]=bch(A0.x); f1a[1]=bch(A0.y); f1a[2]=bch(A0.z); f1a[3]=bch(A0.w);
    f1a[4]=bch(A1.x); f1a[5]=bch(A1.y); f1a[6]=bch(A1.z); f1a[7]=bch(A1.w);
    f1b[0]=bch(B0.x); f1b[1]=bch(B0.y); f1b[2]=bch(B0.z); f1b[3]=bch(B0.w);
    f1b[4]=bch(B1.x); f1b[5]=bch(B1.y); f1b[6]=bch(B1.z); f1b[7]=bch(B1.w);
    float f1sqa = 0.f, f1sqb = 0.f;
#pragma unroll
    for (int k = 0; k < 8; ++k) {
        f1sqa = DOT2(f1a[k], f1a[k], f1sqa);
        f1sqb = DOT2(f1b[k], f1b[k], f1sqb);
    }
    const float c0a = mg * f1sqa;
    const float c0b = mg * f1sqb;

    float s0 = 0.f, x00 = 0.f, x01 = 0.f;
    float s1 = 0.f, x10 = 0.f, x11 = 0.f;

#pragma unroll
    for (int r = 0; r < 2; ++r) {
        if (r < nr) {
            const int dyc = wh + r * 8;          // wave-uniform
            const bool has0 = (dyc <= 8);
            const bool has1 = (dyc >= 1);
            const int rib = dyc * 72 + px;
#pragma unroll
            for (int j = 0; j < 9; ++j) {
                const uint4  q0 = shA[rib + j];
                const uint4  q1 = shB[rib + j];
                const float2 rc = shC[rib + j];
                const f16x2 v0 = bch(q0.x), v1 = bch(q0.y), v2 = bch(q0.z), v3 = bch(q0.w);
                const f16x2 v4 = bch(q1.x), v5 = bch(q1.y), v6 = bch(q1.z), v7 = bch(q1.w);
                const f16x2 oh = bch(__builtin_bit_cast(unsigned, rc.x));
                const float o0f = (float)oh.x, o1f = (float)oh.y;
                const float f2s = rc.y;
                if (has0) {
                    float dt = DOT2(f1a[0], v0, 0.f);
                    dt = DOT2(f1a[1], v1, dt); dt = DOT2(f1a[2], v2, dt);
                    dt = DOT2(f1a[3], v3, dt); dt = DOT2(f1a[4], v4, dt);
                    dt = DOT2(f1a[5], v5, dt); dt = DOT2(f1a[6], v6, dt);
                    dt = DOT2(f1a[7], v7, dt);
                    float e = fmaf(g2, dt, c0a);
                    e = fmaf(mg, f2s, e);
                    e = fmaf(gsl, a0v[r][j], e);
                    const float wgt = EXP2F(e);
                    s0 += wgt; x00 = fmaf(wgt, o0f, x00); x01 = fmaf(wgt, o1f, x01);
                }
                if (has1) {
                    float dt = DOT2(f1b[0], v0, 0.f);
                    dt = DOT2(f1b[1], v1, dt); dt = DOT2(f1b[2], v2, dt);
                    dt = DOT2(f1b[3], v3, dt); dt = DOT2(f1b[4], v4, dt);
                    dt = DOT2(f1b[5], v5, dt); dt = DOT2(f1b[6], v6, dt);
                    dt = DOT2(f1b[7], v7, dt);
                    float e = fmaf(g2, dt, c0b);
                    e = fmaf(mg, f2s, e);
                    e = fmaf(gsl, a1v[r][j], e);
                    const float wgt = EXP2F(e);
                    s1 += wgt; x10 = fmaf(wgt, o0f, x10); x11 = fmaf(wgt, o1f, x11);
                }
            }
        }
    }

    shP[(0 * 8 + wh) * 64 + px] = s0;
    shP[(1 * 8 + wh) * 64 + px] = x00;
    shP[(2 * 8 + wh) * 64 + px] = x01;
    shP[(3 * 8 + wh) * 64 + px] = s1;
    shP[(4 * 8 + wh) * 64 + px] = x10;
    shP[(5 * 8 + wh) * 64 + px] = x11;
    __syncthreads();

    if (t < 64) {
        float v[6];
#pragma unroll
        for (int k = 0; k < 6; ++k) {
            const float* pp = &shP[k * 512 + t];
            v[k] = ((pp[0] + pp[64]) + (pp[128] + pp[192]))
                 + ((pp[256] + pp[320]) + (pp[384] + pp[448]));
        }
        const int pp0 = y0 * 128 + bx + t;
        const float i0 = 1.0f / v[0], i1 = 1.0f / v[3];
        float* o0 = outp + (size_t)(n * 2 + 0) * HW;
        float* o1 = outp + (size_t)(n * 2 + 1) * HW;
        o0[pp0]       = v[1] * i0;
        o1[pp0]       = v[2] * i0;
        o0[pp0 + 128] = v[4] * i1;
        o1[pp0 + 128] = v[5] * i1;
    }
}

extern "C" void kernel_launch(void* const* d_in, const int* in_sizes, int n_in,
                              void* d_out, int out_size, void* d_ws, size_t ws_size,
                              hipStream_t stream) {
    const float* delta = (const float*)d_in[0];   // [4,64,128,128]
    const float* outlo = (const float*)d_in[1];   // [4,2,64,64]
    const float* ab    = (const float*)d_in[2];   // [4,81,16384]
    const float* w1    = (const float*)d_in[3];   // [16,64]
    const float* b1    = (const float*)d_in[4];   // [16]
    const float* w2    = (const float*)d_in[5];   // [16,64]
    const float* b2    = (const float*)d_in[6];   // [16]
    const float* gd    = (const float*)d_in[7];   // scalar
    const float* gs    = (const float*)d_in[8];   // scalar
    float* outp = (float*)d_out;                  // [4,2,128,128]

    uint4*  f1p4 = (uint4*)d_ws;                  // 2 MiB
    uint4*  f2p4 = f1p4 + (size_t)2 * NPIX;       // 2 MiB
    float2* recp = (float2*)(f2p4 + (size_t)2 * NPIX); // 512 KiB

    pass1_kernel<<<dim3(1024), dim3(256), 0, stream>>>(delta, outlo, w1, b1, w2, b2,
                                                       f1p4, f2p4, recp);
    pass2_kernel<<<dim3(2, 64, 4), dim3(512), 0, stream>>>(f1p4, f2p4, recp, ab,
                                                           gd, gs, outp);
}